// Round 1
// baseline (472.837 us; speedup 1.0000x reference)
//
#include <hip/hip_runtime.h>
#include <hip/hip_bf16.h>
#include <cstdint>
#include <cstddef>

#define NB 32
#define NS 4096
#define NH 512
#define NK 1024   // 2H

typedef __attribute__((ext_vector_type(8))) short bf16x8;
typedef __attribute__((ext_vector_type(4))) float f32x4;

__device__ __forceinline__ short f2bf_s(float f) {
  union { float f; unsigned u; } x; x.f = f;
  unsigned r = x.u + 0x7fffu + ((x.u >> 16) & 1u);   // RNE bf16
  return (short)(r >> 16);
}

// ---- kernel 1: convert Ua_w [512][1024] f32 -> bf16 ----
__global__ void k_ua_cvt(const float* __restrict__ ua, unsigned short* __restrict__ out) {
  int i = (blockIdx.x * 256 + threadIdx.x) * 4;
  float4 v = *(const float4*)(ua + i);
  ushort4 o;
  o.x = (unsigned short)f2bf_s(v.x);
  o.y = (unsigned short)f2bf_s(v.y);
  o.z = (unsigned short)f2bf_s(v.z);
  o.w = (unsigned short)f2bf_s(v.w);
  *(ushort4*)(out + i) = o;
}

// ---- kernel 2: qproj[b][h] = query[b]·Wa_w[h] + Wa_b[h] + Ua_b[h] ----
__global__ void k_qproj(const float* __restrict__ q, const float* __restrict__ ww,
                        const float* __restrict__ wb, const float* __restrict__ ub,
                        float* __restrict__ qp) {
  int b = blockIdx.y;
  int h = blockIdx.x * 128 + threadIdx.x;
  const float* qr = q + b * NH;
  const float* wr = ww + h * NH;
  float acc = 0.f;
  for (int k = 0; k < NH; k += 4) {
    float4 a = *(const float4*)(qr + k);
    float4 c = *(const float4*)(wr + k);
    acc += a.x * c.x + a.y * c.y + a.z * c.z + a.w * c.w;
  }
  qp[b * NH + h] = acc + wb[h] + ub[h];
}

// ---- kernel 3: scores[b][s] = Va·tanh(qproj + keys·Ua^T) + Va_b ----
// block: 512 threads = 8 waves, BM=128 s-rows (16 per wave), full N=512 in acc.
__global__ __launch_bounds__(512, 2)
void k_scores(const float* __restrict__ keys, const unsigned short* __restrict__ uabf,
              const float* __restrict__ qproj, const float* __restrict__ vaw,
              const float* __restrict__ vab, float* __restrict__ scores) {
  __shared__ uint4 lds4[2560];      // 512 Ua-rows x 80B (32 bf16 + 16B pad)
  __shared__ float va_s[512];
  __shared__ float qp_s[512];

  const int b   = blockIdx.y;
  const int s0  = blockIdx.x * 128;
  const int tid = threadIdx.x;
  const int w   = tid >> 6;
  const int l   = tid & 63;
  const int col = l & 15;
  const int g   = l >> 4;

  va_s[tid] = vaw[tid];
  qp_s[tid] = qproj[b * NH + tid];

  f32x4 zero = {0.f, 0.f, 0.f, 0.f};
  f32x4 acc[32];
  #pragma unroll
  for (int i = 0; i < 32; ++i) acc[i] = zero;

  const float* arow = keys + ((size_t)b * NS + (size_t)(s0 + w * 16 + col)) * NK;

  for (int ks = 0; ks < 32; ++ks) {
    const int k0 = ks * 32;
    __syncthreads();   // protect previous iteration's LDS reads
    // stage Ua[n=0..511][k0..k0+32) as bf16 into LDS (80B stride)
    #pragma unroll
    for (int i = 0; i < 4; ++i) {
      int c = (i << 9) | tid;        // 2048 16B-chunks
      int n = c >> 2, kc = c & 3;
      uint4 v = *(const uint4*)(uabf + (n << 10) + k0 + (kc << 3));
      lds4[n * 5 + kc] = v;
    }
    __syncthreads();

    // A fragment straight from global: 8 f32 -> 8 bf16
    const float* ap = arow + k0 + g * 8;
    float4 a0 = *(const float4*)(ap);
    float4 a1 = *(const float4*)(ap + 4);
    bf16x8 af;
    af[0] = f2bf_s(a0.x); af[1] = f2bf_s(a0.y); af[2] = f2bf_s(a0.z); af[3] = f2bf_s(a0.w);
    af[4] = f2bf_s(a1.x); af[5] = f2bf_s(a1.y); af[6] = f2bf_s(a1.z); af[7] = f2bf_s(a1.w);

    #pragma unroll
    for (int nt = 0; nt < 32; ++nt) {
      int n = (nt << 4) | col;
      bf16x8 bf = *(const bf16x8*)&lds4[n * 5 + g];
      acc[nt] = __builtin_amdgcn_mfma_f32_16x16x32_bf16(af, bf, acc[nt], 0, 0, 0);
    }
  }

  // epilogue: score[row] = sum_n Va[n]*tanh(qproj[n] + kproj[row][n])
  #pragma unroll
  for (int j = 0; j < 4; ++j) {
    float sc = 0.f;
    #pragma unroll
    for (int nt = 0; nt < 32; ++nt) {
      int n = (nt << 4) | col;
      sc += va_s[n] * tanhf(qp_s[n] + acc[nt][j]);
    }
    sc += __shfl_xor(sc, 1);
    sc += __shfl_xor(sc, 2);
    sc += __shfl_xor(sc, 4);
    sc += __shfl_xor(sc, 8);
    if (col == 0)
      scores[(size_t)b * NS + s0 + w * 16 + g * 4 + j] = sc + vab[0];
  }
}

// ---- kernel 4: softmax over scores rows -> attn out ----
__global__ void k_softmax(const float* __restrict__ scores, float* __restrict__ attn) {
  __shared__ float redm[4];
  __shared__ float reds[4];
  int b = blockIdx.x, tid = threadIdx.x;
  const float* row = scores + (size_t)b * NS;
  float v[16];
  float m = -1e30f;
  #pragma unroll
  for (int i = 0; i < 16; ++i) { v[i] = row[i * 256 + tid]; m = fmaxf(m, v[i]); }
  #pragma unroll
  for (int off = 1; off < 64; off <<= 1) m = fmaxf(m, __shfl_xor(m, off));
  if ((tid & 63) == 0) redm[tid >> 6] = m;
  __syncthreads();
  m = fmaxf(fmaxf(redm[0], redm[1]), fmaxf(redm[2], redm[3]));
  float s = 0.f;
  #pragma unroll
  for (int i = 0; i < 16; ++i) { v[i] = expf(v[i] - m); s += v[i]; }
  #pragma unroll
  for (int off = 1; off < 64; off <<= 1) s += __shfl_xor(s, off);
  if ((tid & 63) == 0) reds[tid >> 6] = s;
  __syncthreads();
  s = reds[0] + reds[1] + reds[2] + reds[3];
  float inv = 1.f / s;
  float* o = attn + (size_t)b * NS;
  #pragma unroll
  for (int i = 0; i < 16; ++i) o[i * 256 + tid] = v[i] * inv;
}

// ---- kernel 5: context partials: part[seg][b][c] = sum_{s in seg} w[b][s]*keys[b][s][c] ----
__global__ void k_ctx_partial(const float* __restrict__ keys, const float* __restrict__ attn,
                              float* __restrict__ part) {
  __shared__ float w_s[256];
  int b = blockIdx.y, seg = blockIdx.x, tid = threadIdx.x;
  int sbeg = seg * 256;
  w_s[tid] = attn[(size_t)b * NS + sbeg + tid];
  __syncthreads();
  const float* kp = keys + ((size_t)b * NS + sbeg) * NK + tid * 4;
  float ax = 0.f, ay = 0.f, az = 0.f, aw = 0.f;
  #pragma unroll 4
  for (int s = 0; s < 256; ++s) {
    float4 kv = *(const float4*)(kp + (size_t)s * NK);
    float wv = w_s[s];
    ax += wv * kv.x; ay += wv * kv.y; az += wv * kv.z; aw += wv * kv.w;
  }
  float4 o; o.x = ax; o.y = ay; o.z = az; o.w = aw;
  *(float4*)(part + ((size_t)(seg * NB + b) << 10) + tid * 4) = o;
}

// ---- kernel 6: reduce 16 segment partials -> context out ----
__global__ void k_ctx_reduce(const float* __restrict__ part, float* __restrict__ ctx) {
  int i = blockIdx.x * 256 + threadIdx.x;   // 32768
  int b = i >> 10, c = i & 1023;
  float s = 0.f;
  #pragma unroll
  for (int seg = 0; seg < 16; ++seg) s += part[((size_t)(seg * NB + b) << 10) + c];
  ctx[i] = s;
}

extern "C" void kernel_launch(void* const* d_in, const int* in_sizes, int n_in,
                              void* d_out, int out_size, void* d_ws, size_t ws_size,
                              hipStream_t stream) {
  const float* query = (const float*)d_in[0];
  const float* keys  = (const float*)d_in[1];
  const float* Wa_w  = (const float*)d_in[2];
  const float* Wa_b  = (const float*)d_in[3];
  const float* Ua_w  = (const float*)d_in[4];
  const float* Ua_b  = (const float*)d_in[5];
  const float* Va_w  = (const float*)d_in[6];
  const float* Va_b  = (const float*)d_in[7];

  float* out      = (float*)d_out;
  float* ctx_out  = out;             // [32][1024]
  float* attn_out = out + NB * NK;   // [32][4096]

  unsigned short* ua_bf = (unsigned short*)d_ws;                                  // 1 MB
  float* qproj  = (float*)((char*)d_ws + (1u << 20));                             // 64 KB
  float* scores = (float*)((char*)d_ws + (1u << 20) + (1u << 16));                // 512 KB
  float* part   = (float*)((char*)d_ws + (1u << 20) + (1u << 16) + (1u << 19));   // 2 MB

  k_ua_cvt<<<512, 256, 0, stream>>>(Ua_w, ua_bf);
  k_qproj<<<dim3(4, NB), 128, 0, stream>>>(query, Wa_w, Wa_b, Ua_b, qproj);
  k_scores<<<dim3(NS / 128, NB), 512, 0, stream>>>(keys, ua_bf, qproj, Va_w, Va_b, scores);
  k_softmax<<<NB, 256, 0, stream>>>(scores, attn_out);
  k_ctx_partial<<<dim3(16, NB), 256, 0, stream>>>(keys, attn_out, part);
  k_ctx_reduce<<<NB * NK / 256, 256, 0, stream>>>(part, ctx_out);
}